// Round 20
// baseline (332.428 us; speedup 1.0000x reference)
//
#include <hip/hip_runtime.h>
#include <hip/hip_bf16.h>

#define CC 96

typedef short short8  __attribute__((ext_vector_type(8)));
typedef short short4v __attribute__((ext_vector_type(4)));
typedef float f32x4   __attribute__((ext_vector_type(4)));
typedef _Float16 half4 __attribute__((ext_vector_type(4)));

#if __has_builtin(__builtin_amdgcn_mfma_f32_16x16x16_f16)
  #define MFMA16(a,b,c) __builtin_amdgcn_mfma_f32_16x16x16_f16((a),(b),(c),0,0,0)
#else
  #define MFMA16(a,b,c) __builtin_amdgcn_mfma_f32_16x16x16f16((a),(b),(c),0,0,0)
#endif

static __device__ __forceinline__ ushort f2bf(float f) {
  __hip_bfloat16 h = __float2bfloat16(f);
  return *reinterpret_cast<ushort*>(&h);
}
static __device__ __forceinline__ float bf2f(ushort u) {
  union { unsigned int u; float f; } v; v.u = ((unsigned int)u) << 16; return v.f;
}

#define QSCALE 0.20412414523193154f
#define LOG2E  1.4426950408889634f

// ---------------- prep: pack all weights (norm folds + log2e fold) ----------------
__global__ void prep_kernel(const float* __restrict__ qkv_w,
                            const float* __restrict__ qkv_b,
                            const float* __restrict__ proj_w,
                            const float* __restrict__ w2w,
                            const float* __restrict__ w1w,
                            const float* __restrict__ norm_w,
                            const float* __restrict__ mlp_norm_w,
                            __hip_bfloat16* __restrict__ qkvp,
                            float* __restrict__ qkvb2,
                            __hip_bfloat16* __restrict__ projp,
                            __hip_bfloat16* __restrict__ w2p,
                            __hip_bfloat16* __restrict__ w1p,
                            __hip_bfloat16* __restrict__ vwp)
{
  const int i = blockIdx.x*256 + threadIdx.x;
  if (i < 36864) {
    const int e = i & 7, lane = (i >> 3) & 63;
    const int rest = i >> 9;           // (h*3+ks)*6+mt
    const int mt = rest % 6, r2 = rest / 6;
    const int ks = r2 % 3, h = r2 / 3;
    const int od = mt*16 + (lane & 15);
    const int sec = od >> 5, d = od & 31;
    const int c = ks*32 + (lane >> 4)*8 + e;
    float val = 0.f;
    if (d < 24) {
      val = qkv_w[(sec*96 + h*24 + d)*96 + c] * norm_w[c];   // norm fold
      if (sec == 0) val *= QSCALE * LOG2E;                   // scale + log2e fold (Q only)
    }
    qkvp[i] = __float2bfloat16(val);
  }
  const int jb = i - 36864;
  if (jb >= 0 && jb < 384) {
    const int h = jb / 96, od = jb - h*96;
    const int sec = od >> 5, d = od & 31;
    float val = 0.f;
    if (d < 24) {
      val = qkv_b[sec*96 + h*24 + d];
      if (sec == 0) val *= QSCALE * LOG2E;
    }
    qkvb2[jb] = val;
  }
  const int j = i - 37248;
  if (j >= 0 && j < 9216) {
    const int e = j & 7, lane = (j >> 3) & 63;
    const int rest = j >> 9;           // ks*6+nt
    const int nt = rest % 6, ks = rest / 6;
    const int oc = nt*16 + (lane & 15);
    const int dd = ks*32 + (lane >> 4)*8 + e;
    projp[j] = __float2bfloat16(proj_w[oc*96 + dd]);
  }
  const int k = i - 46464;
  if (k >= 0 && k < 82944) {
    const int e = k & 7;
    const int lane = (k >> 3) & 63;
    const int rest = k >> 9;           // (tap*3+kc)*6+nf
    const int nf = rest % 6;
    const int r2 = rest / 6;
    const int kc = r2 % 3;
    const int tap = r2 / 3;
    const int cidx = kc*32 + (lane >> 4)*8 + e;
    const int oc = nf*16 + (lane & 15);
    const int ky = tap / 3, kx = tap - ky*3;
    w2p[k] = __float2bfloat16(w2w[((oc*96 + cidx)*3 + ky)*3 + kx]);
  }
  const int m = i - 129408;
  if (m >= 0 && m < 18432) {
    const int e = m & 7, lane = (m >> 3) & 63;
    const int rest = m >> 9;           // ks*12+nt
    const int nt = rest % 12, ks = rest / 12;
    const int oc = nt*16 + (lane & 15);
    const int c  = ks*32 + (lane >> 4)*8 + e;
    w1p[m] = __float2bfloat16(w1w[oc*96 + c] * mlp_norm_w[c]);   // norm fold
  }
  const int v = i - 147840;
  if (v >= 0 && v < 12288) {
    const int e = v & 7, lane = (v >> 3) & 63;
    const int rest = v >> 9;           // (h*3+ks)*2+nt2
    const int nt2 = rest % 2, r2 = rest / 2;
    const int ks = r2 % 3, h = r2 / 3;
    const int d = nt2*16 + (lane & 15);
    const int c = ks*32 + (lane >> 4)*8 + e;
    const float val = (d < 24) ? qkv_w[(192 + h*24 + d)*96 + c] * norm_w[c] : 0.f;
    vwp[v] = __float2bfloat16(val);
  }
}

// ---------------- Kernel 1: windowed MHA — register-resident; residual fused at proj ----------------
// x1b != null: write x1 bf16 wp-tiled [b][96][512][128]; else write f32 out.
// LDS 52,100B -> 3 blocks/CU (launch_bounds 6 waves/EU).
__global__ __launch_bounds__(512, 6) void attn_kernel(
    const float* __restrict__ x,
    const __hip_bfloat16* __restrict__ qkvp,
    const float* __restrict__ qkvb2,
    const __hip_bfloat16* __restrict__ vwp,
    const __hip_bfloat16* __restrict__ projp,
    const float* __restrict__ proj_b,
    const float* __restrict__ bias_table,
    float* __restrict__ out,
    ushort* __restrict__ x1b)
{
  extern __shared__ char smem[];
  ushort* xn   = (ushort*)smem;              // [128][104] bf16: xn -> o -> outT[96][132]
  ushort* xr   = (ushort*)(smem + 26624);    // [128][96]  raw x bf16 (residual source)
  float*  btab = (float*)(smem + 51200);     // [225] (pre-scaled by log2e)

  const int wp = blockIdx.x;                 // window pair
  const int b   = wp >> 9;
  const int wpl = wp & 511;
  const int wy  = (wp >> 4) & 31;
  const int wxp = wp & 15;
  const int t  = threadIdx.x;
  const int y0 = wy*8, x0 = wxp*16;
  const int l  = t & 63;
  const int W  = __builtin_amdgcn_readfirstlane(t >> 6);
  const int w2 = W >> 2, h = W & 3;
  const int lr = l & 15, g = l >> 4;

  for (int i = t; i < 225; i += 512) btab[i] = bias_table[i] * LOG2E;

  // ---- P1: coalesced load + in-register RMS scale -> xn bf16 ; raw x -> xr bf16 ----
  {
    const int p = t >> 2, q = t & 3;         // pixel 0..127, channel quarter
    const int ty = p >> 4, tx = p & 15;
    const float* xp = x + (size_t)(b*CC + q*24)*65536 + (size_t)(y0+ty)*256 + x0 + tx;
    float xv[24]; float ss = 0.f;
    #pragma unroll
    for (int i = 0; i < 24; i++) { xv[i] = xp[(size_t)i*65536]; ss += xv[i]*xv[i]; }
    ss += __shfl_xor(ss, 1);
    ss += __shfl_xor(ss, 2);
    const float s = rsqrtf(ss * (1.f/96.f) + 1e-6f);
    const int row = (tx >> 3)*64 + ty*8 + (tx & 7);
    #pragma unroll
    for (int k2 = 0; k2 < 3; k2++) {
      short8 pk, pr;
      #pragma unroll
      for (int q2 = 0; q2 < 8; q2++) {
        pr[q2] = (short)f2bf(xv[k2*8+q2]);
        pk[q2] = (short)f2bf(xv[k2*8+q2] * s);     // norm_w folded into weights
      }
      *(short8*)(xn + row*104 + q*24 + k2*8) = pk;
      *(short8*)(xr + row*96  + q*24 + k2*8) = pr;
    }
  }
  __syncthreads();   // (A)

  // ---- P2: transposed Q/K GEMM in 2 low-pressure passes ----
  half4 qf[2][4], kf[2][4];
  __builtin_amdgcn_s_setprio(1);
  #pragma unroll
  for (int pass = 0; pass < 2; pass++) {     // 0 -> Q, 1 -> K
    f32x4 acc[2][4];
    #pragma unroll
    for (int m2 = 0; m2 < 2; m2++)
      #pragma unroll
      for (int nt = 0; nt < 4; nt++) acc[m2][nt] = (f32x4)0.f;
    #pragma unroll
    for (int ks = 0; ks < 3; ks++) {
      short8 bfr[4];
      #pragma unroll
      for (int nt = 0; nt < 4; nt++)
        bfr[nt] = *(const short8*)((const char*)xn + (w2*64 + nt*16 + lr)*208 + g*16 + ks*64);
      #pragma unroll
      for (int m2 = 0; m2 < 2; m2++) {
        const short8 afr = *(const short8*)(qkvp + ((h*3+ks)*6 + pass*2 + m2)*512 + l*8);
        #pragma unroll
        for (int nt = 0; nt < 4; nt++)
          acc[m2][nt] = __builtin_amdgcn_mfma_f32_16x16x32_bf16(afr, bfr[nt], acc[m2][nt], 0, 0, 0);
      }
    }
    #pragma unroll
    for (int m2 = 0; m2 < 2; m2++) {
      const f32x4 bb = *(const f32x4*)(qkvb2 + h*96 + (pass*2+m2)*16 + g*4);
      #pragma unroll
      for (int nt = 0; nt < 4; nt++)
        #pragma unroll
        for (int r = 0; r < 4; r++) {
          const float v = acc[m2][nt][r] + bb[r];
          if (pass == 0) qf[m2][nt][r] = (_Float16)v;
          else           kf[m2][nt][r] = (_Float16)v;
        }
    }
  }
  __builtin_amdgcn_s_setprio(0);

  // ---- P3+P4 fused per qt: scores (log2 domain) + softmax via exp2 -> pa ----
  half4 pa[4][4];   // [kt][qt]
  #pragma unroll
  for (int qt = 0; qt < 4; qt++) {
    f32x4 sacc[4];
    __builtin_amdgcn_s_setprio(1);
    #pragma unroll
    for (int kt = 0; kt < 4; kt++) {
      f32x4 s0 = MFMA16(kf[0][kt], qf[0][qt], (f32x4)0.f);
      sacc[kt] = MFMA16(kf[1][kt], qf[1][qt], s0);
    }
    __builtin_amdgcn_s_setprio(0);
    const int q = qt*16 + lr;
    const int aq = (q >> 3)*15 + (q & 7);
    float vv[4][4];
    float mx = -1e30f;
    #pragma unroll
    for (int kt = 0; kt < 4; kt++)
      #pragma unroll
      for (int r = 0; r < 4; r++) {
        const int k = kt*16 + g*4 + r;
        vv[kt][r] = sacc[kt][r] + btab[aq + 112 - ((k >> 3)*15 + (k & 7))];
        mx = fmaxf(mx, vv[kt][r]);
      }
    mx = fmaxf(mx, __shfl_xor(mx, 16));
    mx = fmaxf(mx, __shfl_xor(mx, 32));
    float sum = 0.f;
    #pragma unroll
    for (int kt = 0; kt < 4; kt++)
      #pragma unroll
      for (int r = 0; r < 4; r++) { vv[kt][r] = exp2f(vv[kt][r] - mx); sum += vv[kt][r]; }
    sum += __shfl_xor(sum, 16);
    sum += __shfl_xor(sum, 32);
    const float rinv = 1.f / sum;
    #pragma unroll
    for (int kt = 0; kt < 4; kt++)
      #pragma unroll
      for (int r = 0; r < 4; r++) pa[kt][qt][r] = (_Float16)(vv[kt][r] * rinv);
  }

  // ---- P2c: V GEMM, NON-transposed -> C IS the PV B-frag layout ----
  half4 vb[4][2];   // [kt(tok-tile)][nt2]
  {
    f32x4 vacc[4][2];
    #pragma unroll
    for (int kt = 0; kt < 4; kt++) { vacc[kt][0] = (f32x4)0.f; vacc[kt][1] = (f32x4)0.f; }
    __builtin_amdgcn_s_setprio(1);
    #pragma unroll
    for (int ks = 0; ks < 3; ks++) {
      short8 afr[4];
      #pragma unroll
      for (int kt = 0; kt < 4; kt++)
        afr[kt] = *(const short8*)((const char*)xn + (w2*64 + kt*16 + lr)*208 + g*16 + ks*64);
      #pragma unroll
      for (int nt2 = 0; nt2 < 2; nt2++) {
        const short8 vwf = *(const short8*)(vwp + ((h*3+ks)*2+nt2)*512 + l*8);
        #pragma unroll
        for (int kt = 0; kt < 4; kt++)
          vacc[kt][nt2] = __builtin_amdgcn_mfma_f32_16x16x32_bf16(afr[kt], vwf, vacc[kt][nt2], 0, 0, 0);
      }
    }
    __builtin_amdgcn_s_setprio(0);
    #pragma unroll
    for (int nt2 = 0; nt2 < 2; nt2++) {
      const float vbias = qkvb2[h*96 + 64 + nt2*16 + lr];
      #pragma unroll
      for (int kt = 0; kt < 4; kt++)
        #pragma unroll
        for (int r = 0; r < 4; r++)
          vb[kt][nt2][r] = (_Float16)(vacc[kt][nt2][r] + vbias);
    }
  }

  // ---- P5: PV fully in-register ----
  f32x4 oacc[4][2];
  #pragma unroll
  for (int qt = 0; qt < 4; qt++) { oacc[qt][0] = (f32x4)0.f; oacc[qt][1] = (f32x4)0.f; }
  __builtin_amdgcn_s_setprio(1);
  #pragma unroll
  for (int kt = 0; kt < 4; kt++)
    #pragma unroll
    for (int qt = 0; qt < 4; qt++) {
      oacc[qt][0] = MFMA16(pa[kt][qt], vb[kt][0], oacc[qt][0]);
      oacc[qt][1] = MFMA16(pa[kt][qt], vb[kt][1], oacc[qt][1]);
    }
  __builtin_amdgcn_s_setprio(0);
  __syncthreads();   // (B) all xn reads done; o may overwrite

  #pragma unroll
  for (int qt = 0; qt < 4; qt++)
    #pragma unroll
    for (int r = 0; r < 4; r++) {
      const int row = w2*64 + qt*16 + g*4 + r;
      xn[row*104 + h*24 + lr] = f2bf(oacc[qt][0][r]);
      if (lr < 8) xn[row*104 + h*24 + 16 + lr] = f2bf(oacc[qt][1][r]);
    }
  __syncthreads();   // (C) o complete

  // ---- P6: proj (wave W owns mtile W), K=96; residual added from xr at write ----
  {
    f32x4 pacc[6];
    #pragma unroll
    for (int nt = 0; nt < 6; nt++) pacc[nt] = (f32x4)0.f;
    __builtin_amdgcn_s_setprio(1);
    #pragma unroll
    for (int ks = 0; ks < 3; ks++) {
      const short8 af = *(const short8*)((const char*)xn + (lr + W*16)*208 + g*16 + ks*64);
      #pragma unroll
      for (int nt = 0; nt < 6; nt++) {
        const short8 bf = *(const short8*)(projp + (ks*6+nt)*512 + l*8);
        pacc[nt] = __builtin_amdgcn_mfma_f32_16x16x32_bf16(af, bf, pacc[nt], 0, 0, 0);
      }
    }
    __builtin_amdgcn_s_setprio(0);
    __syncthreads();   // (D) all o reads done; xn becomes outT[96][132]
    ushort* oT = xn;
    #pragma unroll
    for (int nt = 0; nt < 6; nt++) {
      const int oc = lr + nt*16;
      const float bias = proj_b[oc];
      short4v pk;
      #pragma unroll
      for (int r = 0; r < 4; r++) {
        const int row = W*16 + g*4 + r;
        pk[r] = (short)f2bf(pacc[nt][r] + bias + bf2f(xr[row*96 + oc]));
      }
      *(short4v*)((char*)oT + oc*264 + (g*4 + W*16)*2) = pk;
    }
  }
  __syncthreads();   // (E)

  // ---- epilogue ----
  if (x1b) {
    const ushort* oT = xn;
    #pragma unroll
    for (int k2 = 0; k2 < 6; k2++) {
      const int e = t + k2*512;
      const int oc = e >> 5, q5 = e & 31;
      const int ty = q5 >> 2, tq = q5 & 3;
      const int m = (tq >> 1)*64 + ty*8 + (tq & 1)*4;
      const short4v ov = *(const short4v*)((const char*)oT + oc*264 + m*2);
      *(short4v*)(x1b + ((size_t)(b*96+oc)*512 + wpl)*128 + m) = ov;
    }
  } else {
    const ushort* oT = xn;
    #pragma unroll
    for (int k2 = 0; k2 < 6; k2++) {
      const int e = t + k2*512;
      const int oc = e >> 5, q5 = e & 31;
      const int ty = q5 >> 2, tq = q5 & 3;
      const int m = (tq >> 1)*64 + ty*8 + (tq & 1)*4;
      const short4v ov = *(const short4v*)((const char*)oT + oc*264 + m*2);
      const size_t gidx = (size_t)(b*CC+oc)*65536 + (size_t)(y0+ty)*256 + x0 + tq*4;
      float4 res;
      res.x = bf2f((ushort)ov[0]);
      res.y = bf2f((ushort)ov[1]);
      res.z = bf2f((ushort)ov[2]);
      res.w = bf2f((ushort)ov[3]);
      *(float4*)(out + gidx) = res;
    }
  }
}

// ---------------- Kernel 2: RMSNorm + conv1x1 + GLU via MFMA -> y bf16 [b][hw][96] ----------------
__global__ __launch_bounds__(256, 3) void mlp1_kernel(
    const float* __restrict__ x1f,
    const ushort* __restrict__ x1b,
    const __hip_bfloat16* __restrict__ w1p,   // [ks][12][64][8] (mlp_norm_w folded)
    const float* __restrict__ w1_b,
    __hip_bfloat16* __restrict__ y)           // [b][hw][96]
{
  __shared__ ushort xn[128*104];
  const int blk = blockIdx.x;
  const int b   = blk >> 9;
  const int wpl = blk & 511;
  const int wy  = wpl >> 4, wxp = wpl & 15;
  const int t   = threadIdx.x;
  const int l   = t & 63;
  const int w   = __builtin_amdgcn_readfirstlane(t >> 6);
  const int lr  = l & 15, g = l >> 4;

  {
    const int p = t >> 1, half = t & 1;
    float xv[48];
    float ss = 0.f;
    if (x1b) {
      const ushort* xp = x1b + ((size_t)(b*96 + half*48)*512 + wpl)*128 + p;
      #pragma unroll
      for (int i = 0; i < 48; i++) { xv[i] = bf2f(xp[(size_t)i*65536]); ss += xv[i]*xv[i]; }
    } else {
      const int gy = wy*8 + ((p & 63) >> 3);
      const int gx = wxp*16 + (p >> 6)*8 + (p & 7);
      const float* xp = x1f + (size_t)(b*CC + half*48)*65536 + (size_t)gy*256 + gx;
      #pragma unroll
      for (int i = 0; i < 48; i++) { xv[i] = xp[(size_t)i*65536]; ss += xv[i]*xv[i]; }
    }
    ss += __shfl_xor(ss, 1);
    const float s = rsqrtf(ss*(1.f/96.f) + 1e-6f);
    #pragma unroll
    for (int i = 0; i < 48; i += 2) {
      const int c = half*48 + i;
      union { ushort u[2]; uint v; } pk;
      pk.u[0] = f2bf(xv[i]   * s);     // mlp_norm_w folded into w1p
      pk.u[1] = f2bf(xv[i+1] * s);
      *(uint*)(&xn[p*104 + c]) = pk.v;
    }
  }
  // wave-private rows -> no barrier needed before GEMM

  f32x4 acc[2][12];
  #pragma unroll
  for (int m2 = 0; m2 < 2; m2++)
    #pragma unroll
    for (int nt = 0; nt < 12; nt++) acc[m2][nt] = (f32x4)0.f;

  #pragma unroll
  for (int ks = 0; ks < 3; ks++) {
    short8 afr[2];
    #pragma unroll
    for (int m2 = 0; m2 < 2; m2++)
      afr[m2] = *(const short8*)((const char*)xn + (lr + (w*2+m2)*16)*208 + g*16 + ks*64);
    #pragma unroll
    for (int nt = 0; nt < 12; nt++) {
      const short8 bfr = *(const short8*)(w1p + ((ks*12+nt)*64 + l)*8);
      #pragma unroll
      for (int m2 = 0; m2 < 2; m2++)
        acc[m2][nt] = __builtin_amdgcn_mfma_f32_16x16x32_bf16(afr[m2], bfr, acc[m2][nt], 0, 0, 0);
    }
  }

  #pragma unroll
  for (int m2 = 0; m2 < 2; m2++)
    #pragma unroll
    for (int nt = 0; nt < 6; nt++) {
      const int oc = nt*16 + lr;
      const float ab = w1_b[oc], gb = w1_b[96+oc];
      #pragma unroll
      for (int r = 0; r < 4; r++) {
        const int row = (w*2+m2)*16 + g*4 + r;
        const float a  = acc[m2][nt][r]   + ab;
        const float gg = acc[m2][nt+6][r] + gb;
        xn[row*104 + oc] = f2bf(a / (1.f + __expf(-gg)));
      }
    }
  __syncthreads();

  // ---- y stores: map local px -> global pixel ----
  #pragma unroll
  for (int k2 = 0; k2 < 6; k2++) {
    const int e = t + k2*256;
    const int p = e / 12, ch = e - p*12;
    const int gy = wy*8 + ((p & 63) >> 3);
    const int gx = wxp*16 + (p >> 6)*8 + (p & 7);
    const short8 v = *(const short8*)(&xn[p*104 + ch*8]);
    *(short8*)((ushort*)y + ((size_t)(b*65536 + gy*256 + gx))*96 + ch*8) = v;
  }
}

// ---------------- Kernel 3: conv3x3 — MFMA implicit GEMM with LDS-staged B ----------------
__global__ __launch_bounds__(256, 2) void conv3_kernel(
    const __hip_bfloat16* __restrict__ y,    // [b][hw][96]
    const __hip_bfloat16* __restrict__ w2p,
    const float* __restrict__ w2_b,
    const ushort* __restrict__ x1b,          // bf16 residual (or null)
    float* __restrict__ xout)                // final f32 output
{
  extern __shared__ char smem[];
  ushort* A  = (ushort*)smem;                 // [264 segs][104 pad] bf16
  ushort* Bs = (ushort*)(smem + 54912);       // [3 kc][6 nf][64 lane][8] bf16 (one tap)

  const int vbid = (blockIdx.x & 7)*256 + (blockIdx.x >> 3);
  const int b   = vbid >> 9;
  const int rem = vbid & 511;
  const int ch  = rem >> 7;          // px chunk 0..3
  const int rp  = rem & 127;         // row pair
  const int px0 = ch << 6;
  const int t   = threadIdx.x;
  const int w   = __builtin_amdgcn_readfirstlane(t >> 6);
  const int l   = t & 63;
  const int m15 = l & 15, lh = l >> 4;

  // ---- stage A (104-pad, proven layout) ----
  for (int e = t; e < 3168; e += 256) {
    const int seg  = e / 12;
    const int part = e - seg*12;
    const int ky = seg / 66;
    const int px = seg - ky*66;
    const int gy = min(255, max(0, 2*rp + ky - 1));
    const int gx = min(255, max(0, px0 + px - 1));
    const short8 v = *(const short8*)(y + ((size_t)(b*65536 + gy*256 + gx))*96 + part*8);
    *(short8*)(A + seg*104 + part*8) = v;
  }

  // ---- prefetch residual into registers ----
  f32x4 resid[2][6];
  const int gpx = px0 + 16*w + lh*4;
  if (x1b) {
    #pragma unroll
    for (int rw = 0; rw < 2; rw++) {
      const int gyo = 2*rp + rw;
      const int wpl = (gyo >> 3)*16 + (gpx >> 4);
      const int gx4 = gpx & 15;
      const int m = (gx4 >> 3)*64 + (gyo & 7)*8 + (gx4 & 7);
      #pragma unroll
      for (int nf = 0; nf < 6; nf++) {
        const int oc = nf*16 + m15;
        const short4v rv = *(const short4v*)(x1b + ((size_t)(b*96+oc)*512 + wpl)*128 + m);
        #pragma unroll
        for (int q = 0; q < 4; q++) resid[rw][nf][q] = bf2f((ushort)rv[q]);
      }
    }
  } else {
    #pragma unroll
    for (int rw = 0; rw < 2; rw++)
      #pragma unroll
      for (int nf = 0; nf < 6; nf++) {
        const int oc = nf*16 + m15;
        resid[rw][nf] = *(const f32x4*)(xout + ((size_t)(b*CC + oc))*65536 + (size_t)(2*rp+rw)*256 + gpx);
      }
  }

  // ---- preload tap 0 B-frags into regs ----
  uint2 breg[9];
  {
    const uint2* src = (const uint2*)w2p;
    #pragma unroll
    for (int i = 0; i < 9; i++) breg[i] = src[t + i*256];
  }

  f32x4 acc0[6], acc1[6];
  #pragma unroll
  for (int nf = 0; nf < 6; ++nf) { acc0[nf] = (f32x4)0.f; acc1[nf] = (f32x4)0.f; }

  for (int tap = 0; tap < 9; ++tap) {
    __syncthreads();   // (a) prior tap's Bs reads done
    {
      uint2* dst = (uint2*)Bs;
      #pragma unroll
      for (int i = 0; i < 9; i++) dst[t + i*256] = breg[i];
    }
    if (tap < 8) {
      const uint2* src = (const uint2*)w2p + (tap+1)*2304;
      #pragma unroll
      for (int i = 0; i < 9; i++) breg[i] = src[t + i*256];
    }
    __syncthreads();   // (b) Bs ready (tap 0: A also ready)

    const int ky = tap / 3, kx = tap - ky*3;
    #pragma unroll
    for (int kc = 0; kc < 3; ++kc) {
      const int cb = kc*32 + lh*8;
      const short8 a0 = *(const short8*)(A + ((ky  )*66 + 16*w + m15 + kx)*104 + cb);
      const short8 a1 = *(const short8*)(A + ((ky+1)*66 + 16*w + m15 + kx)*104 + cb);
      #pragma unroll
      for (int nf = 0; nf < 6; ++nf) {
        const short8 bf = *(const short8*)(Bs + ((kc*6+nf)*64 + l)*8);
        acc0[nf] = __builtin_amdgcn_mfma_f32_16x16x32_bf16(a0, bf, acc0[nf], 0, 0, 0);
        acc1[nf] = __builtin_amdgcn_mfma_f32_16x16x32_bf16(a1, bf, acc1[nf], 0, 0, 0);
      }
    }
  }

  // ---- direct-to-global epilogue: bias + leaky + residual ----
  #pragma unroll
  for (int nf = 0; nf < 6; ++nf) {
    const int oc = nf*16 + m15;
    const float bb = w2_b[oc];
    #pragma unroll
    for (int rw = 0; rw < 2; rw++) {
      const f32x4 av = rw ? acc1[nf] : acc0[nf];
      float* op = xout + ((size_t)(b*CC + oc))*65536 + (size_t)(2*rp+rw)*256 + gpx;
      f32x4 r = resid[rw][nf];
      #pragma unroll
      for (int q = 0; q < 4; ++q) {
        float u = av[q] + bb;
        u = (u >= 0.f) ? u : 0.1f*u;
        r[q] += u;
      }
      *(f32x4*)op = r;
    }
  }
}

extern "C" void kernel_launch(void* const* d_in, const int* in_sizes, int n_in,
                              void* d_out, int out_size, void* d_ws, size_t ws_size,
                              hipStream_t stream)
{
  (void)in_sizes; (void)n_in; (void)out_size;
  const float* x      = (const float*)d_in[0];
  const float* norm_w = (const float*)d_in[1];
  const float* qkv_w  = (const float*)d_in[2];
  const float* qkv_b  = (const float*)d_in[3];
  const float* proj_w = (const float*)d_in[4];
  const float* proj_b = (const float*)d_in[5];
  const float* btab   = (const float*)d_in[6];
  const float* mlpnw  = (const float*)d_in[7];
  const float* w1w    = (const float*)d_in[8];
  const float* w1b    = (const float*)d_in[9];
  const float* w2w    = (const float*)d_in[10];
  const float* w2b    = (const float*)d_in[11];
  float* out = (float*)d_out;

  char* ws = (char*)d_ws;
  __hip_bfloat16* y     = (__hip_bfloat16*)ws;                    // 50,331,648 B
  __hip_bfloat16* w2p   = (__hip_bfloat16*)(ws + 50331648);       // 165,888 B
  __hip_bfloat16* qkvp  = (__hip_bfloat16*)(ws + 50497536);       // 73,728 B
  float*          qkvb2 = (float*)(ws + 50571264);                // 1,536 B
  __hip_bfloat16* projp = (__hip_bfloat16*)(ws + 50572800);       // 18,432 B
  __hip_bfloat16* w1p   = (__hip_bfloat16*)(ws + 50591232);       // 36,864 B
  __hip_bfloat16* vwp   = (__hip_bfloat16*)(ws + 50628096);       // 24,576 B
  // bf16 x1 intermediate (wp-tiled), only if workspace allows
  const size_t X1B_OFF = 50652672;
  const size_t X1B_END = X1B_OFF + (size_t)4*96*512*128*2;        // 100,984,320
  ushort* x1b = (ws_size >= X1B_END) ? (ushort*)(ws + X1B_OFF) : nullptr;

  prep_kernel<<<626, 256, 0, stream>>>(qkv_w, qkv_b, proj_w, w2w, w1w, norm_w, mlpnw,
                                       qkvp, qkvb2, projp, w2p, w1p, vwp);

  attn_kernel<<<2048, 512, 52100, stream>>>(x, qkvp, qkvb2, vwp, projp, proj_b, btab,
                                            out, x1b);
  mlp1_kernel<<<2048, 256, 0, stream>>>(out, x1b, w1p, w1b, y);
  conv3_kernel<<<2048, 256, 73344, stream>>>(y, w2p, w2b, x1b, out);
}

// Round 21
// 225.354 us; speedup vs baseline: 1.4751x; 1.4751x over previous
//
#include <hip/hip_runtime.h>
#include <hip/hip_bf16.h>

#define CC 96

typedef short short8  __attribute__((ext_vector_type(8)));
typedef short short4v __attribute__((ext_vector_type(4)));
typedef float f32x4   __attribute__((ext_vector_type(4)));
typedef _Float16 half4 __attribute__((ext_vector_type(4)));

#if __has_builtin(__builtin_amdgcn_mfma_f32_16x16x16_f16)
  #define MFMA16(a,b,c) __builtin_amdgcn_mfma_f32_16x16x16_f16((a),(b),(c),0,0,0)
#else
  #define MFMA16(a,b,c) __builtin_amdgcn_mfma_f32_16x16x16f16((a),(b),(c),0,0,0)
#endif

static __device__ __forceinline__ ushort f2bf(float f) {
  __hip_bfloat16 h = __float2bfloat16(f);
  return *reinterpret_cast<ushort*>(&h);
}
static __device__ __forceinline__ float bf2f(ushort u) {
  union { unsigned int u; float f; } v; v.u = ((unsigned int)u) << 16; return v.f;
}

#define QSCALE 0.20412414523193154f
#define LOG2E  1.4426950408889634f

// ---------------- prep: pack all weights (norm folds + log2e fold) ----------------
__global__ void prep_kernel(const float* __restrict__ qkv_w,
                            const float* __restrict__ qkv_b,
                            const float* __restrict__ proj_w,
                            const float* __restrict__ w2w,
                            const float* __restrict__ w1w,
                            const float* __restrict__ norm_w,
                            const float* __restrict__ mlp_norm_w,
                            __hip_bfloat16* __restrict__ qkvp,
                            float* __restrict__ qkvb2,
                            __hip_bfloat16* __restrict__ projp,
                            __hip_bfloat16* __restrict__ w2p,
                            __hip_bfloat16* __restrict__ w1p,
                            __hip_bfloat16* __restrict__ vwp)
{
  const int i = blockIdx.x*256 + threadIdx.x;
  if (i < 36864) {
    const int e = i & 7, lane = (i >> 3) & 63;
    const int rest = i >> 9;           // (h*3+ks)*6+mt
    const int mt = rest % 6, r2 = rest / 6;
    const int ks = r2 % 3, h = r2 / 3;
    const int od = mt*16 + (lane & 15);
    const int sec = od >> 5, d = od & 31;
    const int c = ks*32 + (lane >> 4)*8 + e;
    float val = 0.f;
    if (d < 24) {
      val = qkv_w[(sec*96 + h*24 + d)*96 + c] * norm_w[c];   // norm fold
      if (sec == 0) val *= QSCALE * LOG2E;                   // scale + log2e fold (Q only)
    }
    qkvp[i] = __float2bfloat16(val);
  }
  const int jb = i - 36864;
  if (jb >= 0 && jb < 384) {
    const int h = jb / 96, od = jb - h*96;
    const int sec = od >> 5, d = od & 31;
    float val = 0.f;
    if (d < 24) {
      val = qkv_b[sec*96 + h*24 + d];
      if (sec == 0) val *= QSCALE * LOG2E;
    }
    qkvb2[jb] = val;
  }
  const int j = i - 37248;
  if (j >= 0 && j < 9216) {
    const int e = j & 7, lane = (j >> 3) & 63;
    const int rest = j >> 9;           // ks*6+nt
    const int nt = rest % 6, ks = rest / 6;
    const int oc = nt*16 + (lane & 15);
    const int dd = ks*32 + (lane >> 4)*8 + e;
    projp[j] = __float2bfloat16(proj_w[oc*96 + dd]);
  }
  const int k = i - 46464;
  if (k >= 0 && k < 82944) {
    const int e = k & 7;
    const int lane = (k >> 3) & 63;
    const int rest = k >> 9;           // (tap*3+kc)*6+nf
    const int nf = rest % 6;
    const int r2 = rest / 6;
    const int kc = r2 % 3;
    const int tap = r2 / 3;
    const int cidx = kc*32 + (lane >> 4)*8 + e;
    const int oc = nf*16 + (lane & 15);
    const int ky = tap / 3, kx = tap - ky*3;
    w2p[k] = __float2bfloat16(w2w[((oc*96 + cidx)*3 + ky)*3 + kx]);
  }
  const int m = i - 129408;
  if (m >= 0 && m < 18432) {
    const int e = m & 7, lane = (m >> 3) & 63;
    const int rest = m >> 9;           // ks*12+nt
    const int nt = rest % 12, ks = rest / 12;
    const int oc = nt*16 + (lane & 15);
    const int c  = ks*32 + (lane >> 4)*8 + e;
    w1p[m] = __float2bfloat16(w1w[oc*96 + c] * mlp_norm_w[c]);   // norm fold
  }
  const int v = i - 147840;
  if (v >= 0 && v < 12288) {
    const int e = v & 7, lane = (v >> 3) & 63;
    const int rest = v >> 9;           // (h*3+ks)*2+nt2
    const int nt2 = rest % 2, r2 = rest / 2;
    const int ks = r2 % 3, h = r2 / 3;
    const int d = nt2*16 + (lane & 15);
    const int c = ks*32 + (lane >> 4)*8 + e;
    const float val = (d < 24) ? qkv_w[(192 + h*24 + d)*96 + c] * norm_w[c] : 0.f;
    vwp[v] = __float2bfloat16(val);
  }
}

// ---------------- Kernel 1: windowed MHA — register-resident; residual fused at proj ----------------
// x1b != null: write x1 bf16 wp-tiled [b][96][512][128]; else write f32 out.
__global__ __launch_bounds__(512, 2) void attn_kernel(
    const float* __restrict__ x,
    const __hip_bfloat16* __restrict__ qkvp,
    const float* __restrict__ qkvb2,
    const __hip_bfloat16* __restrict__ vwp,
    const __hip_bfloat16* __restrict__ projp,
    const float* __restrict__ proj_b,
    const float* __restrict__ bias_table,
    float* __restrict__ out,
    ushort* __restrict__ x1b)
{
  extern __shared__ char smem[];
  ushort* xn   = (ushort*)smem;              // [128][104] bf16: xn -> o -> outT[96][132]
  ushort* xr   = (ushort*)(smem + 26624);    // [128][96]  raw x bf16 (residual source)
  float*  btab = (float*)(smem + 51200);     // [225] (pre-scaled by log2e)

  const int wp = blockIdx.x;                 // window pair
  const int b   = wp >> 9;
  const int wpl = wp & 511;
  const int wy  = (wp >> 4) & 31;
  const int wxp = wp & 15;
  const int t  = threadIdx.x;
  const int y0 = wy*8, x0 = wxp*16;
  const int l  = t & 63;
  const int W  = __builtin_amdgcn_readfirstlane(t >> 6);
  const int w2 = W >> 2, h = W & 3;
  const int lr = l & 15, g = l >> 4;

  for (int i = t; i < 225; i += 512) btab[i] = bias_table[i] * LOG2E;

  // ---- P1: coalesced load + in-register RMS scale -> xn bf16 ; raw x -> xr bf16 ----
  {
    const int p = t >> 2, q = t & 3;         // pixel 0..127, channel quarter
    const int ty = p >> 4, tx = p & 15;
    const float* xp = x + (size_t)(b*CC + q*24)*65536 + (size_t)(y0+ty)*256 + x0 + tx;
    float xv[24]; float ss = 0.f;
    #pragma unroll
    for (int i = 0; i < 24; i++) { xv[i] = xp[(size_t)i*65536]; ss += xv[i]*xv[i]; }
    ss += __shfl_xor(ss, 1);
    ss += __shfl_xor(ss, 2);
    const float s = rsqrtf(ss * (1.f/96.f) + 1e-6f);
    const int row = (tx >> 3)*64 + ty*8 + (tx & 7);
    #pragma unroll
    for (int k2 = 0; k2 < 3; k2++) {
      short8 pk, pr;
      #pragma unroll
      for (int q2 = 0; q2 < 8; q2++) {
        pr[q2] = (short)f2bf(xv[k2*8+q2]);
        pk[q2] = (short)f2bf(xv[k2*8+q2] * s);     // norm_w folded into weights
      }
      *(short8*)(xn + row*104 + q*24 + k2*8) = pk;
      *(short8*)(xr + row*96  + q*24 + k2*8) = pr;
    }
  }
  __syncthreads();   // (A)

  // ---- P2: transposed Q/K GEMM in 2 low-pressure passes ----
  half4 qf[2][4], kf[2][4];
  __builtin_amdgcn_s_setprio(1);
  #pragma unroll
  for (int pass = 0; pass < 2; pass++) {     // 0 -> Q, 1 -> K
    f32x4 acc[2][4];
    #pragma unroll
    for (int m2 = 0; m2 < 2; m2++)
      #pragma unroll
      for (int nt = 0; nt < 4; nt++) acc[m2][nt] = (f32x4)0.f;
    #pragma unroll
    for (int ks = 0; ks < 3; ks++) {
      short8 bfr[4];
      #pragma unroll
      for (int nt = 0; nt < 4; nt++)
        bfr[nt] = *(const short8*)((const char*)xn + (w2*64 + nt*16 + lr)*208 + g*16 + ks*64);
      #pragma unroll
      for (int m2 = 0; m2 < 2; m2++) {
        const short8 afr = *(const short8*)(qkvp + ((h*3+ks)*6 + pass*2 + m2)*512 + l*8);
        #pragma unroll
        for (int nt = 0; nt < 4; nt++)
          acc[m2][nt] = __builtin_amdgcn_mfma_f32_16x16x32_bf16(afr, bfr[nt], acc[m2][nt], 0, 0, 0);
      }
    }
    #pragma unroll
    for (int m2 = 0; m2 < 2; m2++) {
      const f32x4 bb = *(const f32x4*)(qkvb2 + h*96 + (pass*2+m2)*16 + g*4);
      #pragma unroll
      for (int nt = 0; nt < 4; nt++)
        #pragma unroll
        for (int r = 0; r < 4; r++) {
          const float v = acc[m2][nt][r] + bb[r];
          if (pass == 0) qf[m2][nt][r] = (_Float16)v;
          else           kf[m2][nt][r] = (_Float16)v;
        }
    }
  }
  __builtin_amdgcn_s_setprio(0);

  // ---- P3+P4 fused per qt: scores (log2 domain) + softmax via exp2 -> pa ----
  half4 pa[4][4];   // [kt][qt]
  #pragma unroll
  for (int qt = 0; qt < 4; qt++) {
    f32x4 sacc[4];
    __builtin_amdgcn_s_setprio(1);
    #pragma unroll
    for (int kt = 0; kt < 4; kt++) {
      f32x4 s0 = MFMA16(kf[0][kt], qf[0][qt], (f32x4)0.f);
      sacc[kt] = MFMA16(kf[1][kt], qf[1][qt], s0);
    }
    __builtin_amdgcn_s_setprio(0);
    const int q = qt*16 + lr;
    const int aq = (q >> 3)*15 + (q & 7);
    float vv[4][4];
    float mx = -1e30f;
    #pragma unroll
    for (int kt = 0; kt < 4; kt++)
      #pragma unroll
      for (int r = 0; r < 4; r++) {
        const int k = kt*16 + g*4 + r;
        vv[kt][r] = sacc[kt][r] + btab[aq + 112 - ((k >> 3)*15 + (k & 7))];
        mx = fmaxf(mx, vv[kt][r]);
      }
    mx = fmaxf(mx, __shfl_xor(mx, 16));
    mx = fmaxf(mx, __shfl_xor(mx, 32));
    float sum = 0.f;
    #pragma unroll
    for (int kt = 0; kt < 4; kt++)
      #pragma unroll
      for (int r = 0; r < 4; r++) { vv[kt][r] = exp2f(vv[kt][r] - mx); sum += vv[kt][r]; }
    sum += __shfl_xor(sum, 16);
    sum += __shfl_xor(sum, 32);
    const float rinv = 1.f / sum;
    #pragma unroll
    for (int kt = 0; kt < 4; kt++)
      #pragma unroll
      for (int r = 0; r < 4; r++) pa[kt][qt][r] = (_Float16)(vv[kt][r] * rinv);
  }

  // ---- P2c: V GEMM, NON-transposed -> C IS the PV B-frag layout ----
  half4 vb[4][2];   // [kt(tok-tile)][nt2]
  {
    f32x4 vacc[4][2];
    #pragma unroll
    for (int kt = 0; kt < 4; kt++) { vacc[kt][0] = (f32x4)0.f; vacc[kt][1] = (f32x4)0.f; }
    __builtin_amdgcn_s_setprio(1);
    #pragma unroll
    for (int ks = 0; ks < 3; ks++) {
      short8 afr[4];
      #pragma unroll
      for (int kt = 0; kt < 4; kt++)
        afr[kt] = *(const short8*)((const char*)xn + (w2*64 + kt*16 + lr)*208 + g*16 + ks*64);
      #pragma unroll
      for (int nt2 = 0; nt2 < 2; nt2++) {
        const short8 vwf = *(const short8*)(vwp + ((h*3+ks)*2+nt2)*512 + l*8);
        #pragma unroll
        for (int kt = 0; kt < 4; kt++)
          vacc[kt][nt2] = __builtin_amdgcn_mfma_f32_16x16x32_bf16(afr[kt], vwf, vacc[kt][nt2], 0, 0, 0);
      }
    }
    __builtin_amdgcn_s_setprio(0);
    #pragma unroll
    for (int nt2 = 0; nt2 < 2; nt2++) {
      const float vbias = qkvb2[h*96 + 64 + nt2*16 + lr];
      #pragma unroll
      for (int kt = 0; kt < 4; kt++)
        #pragma unroll
        for (int r = 0; r < 4; r++)
          vb[kt][nt2][r] = (_Float16)(vacc[kt][nt2][r] + vbias);
    }
  }

  // ---- P5: PV fully in-register ----
  f32x4 oacc[4][2];
  #pragma unroll
  for (int qt = 0; qt < 4; qt++) { oacc[qt][0] = (f32x4)0.f; oacc[qt][1] = (f32x4)0.f; }
  __builtin_amdgcn_s_setprio(1);
  #pragma unroll
  for (int kt = 0; kt < 4; kt++)
    #pragma unroll
    for (int qt = 0; qt < 4; qt++) {
      oacc[qt][0] = MFMA16(pa[kt][qt], vb[kt][0], oacc[qt][0]);
      oacc[qt][1] = MFMA16(pa[kt][qt], vb[kt][1], oacc[qt][1]);
    }
  __builtin_amdgcn_s_setprio(0);
  __syncthreads();   // (B) all xn reads done; o may overwrite

  #pragma unroll
  for (int qt = 0; qt < 4; qt++)
    #pragma unroll
    for (int r = 0; r < 4; r++) {
      const int row = w2*64 + qt*16 + g*4 + r;
      xn[row*104 + h*24 + lr] = f2bf(oacc[qt][0][r]);
      if (lr < 8) xn[row*104 + h*24 + 16 + lr] = f2bf(oacc[qt][1][r]);
    }
  __syncthreads();   // (C) o complete

  // ---- P6: proj (wave W owns mtile W), K=96; residual added from xr at write ----
  {
    f32x4 pacc[6];
    #pragma unroll
    for (int nt = 0; nt < 6; nt++) pacc[nt] = (f32x4)0.f;
    __builtin_amdgcn_s_setprio(1);
    #pragma unroll
    for (int ks = 0; ks < 3; ks++) {
      const short8 af = *(const short8*)((const char*)xn + (lr + W*16)*208 + g*16 + ks*64);
      #pragma unroll
      for (int nt = 0; nt < 6; nt++) {
        const short8 bf = *(const short8*)(projp + (ks*6+nt)*512 + l*8);
        pacc[nt] = __builtin_amdgcn_mfma_f32_16x16x32_bf16(af, bf, pacc[nt], 0, 0, 0);
      }
    }
    __builtin_amdgcn_s_setprio(0);
    __syncthreads();   // (D) all o reads done; xn becomes outT[96][132]
    ushort* oT = xn;
    #pragma unroll
    for (int nt = 0; nt < 6; nt++) {
      const int oc = lr + nt*16;
      const float bias = proj_b[oc];
      short4v pk;
      #pragma unroll
      for (int r = 0; r < 4; r++) {
        const int row = W*16 + g*4 + r;
        pk[r] = (short)f2bf(pacc[nt][r] + bias + bf2f(xr[row*96 + oc]));
      }
      *(short4v*)((char*)oT + oc*264 + (g*4 + W*16)*2) = pk;
    }
  }
  __syncthreads();   // (E)

  // ---- epilogue ----
  if (x1b) {
    const ushort* oT = xn;
    #pragma unroll
    for (int k2 = 0; k2 < 6; k2++) {
      const int e = t + k2*512;
      const int oc = e >> 5, q5 = e & 31;
      const int ty = q5 >> 2, tq = q5 & 3;
      const int m = (tq >> 1)*64 + ty*8 + (tq & 1)*4;
      const short4v ov = *(const short4v*)((const char*)oT + oc*264 + m*2);
      *(short4v*)(x1b + ((size_t)(b*96+oc)*512 + wpl)*128 + m) = ov;
    }
  } else {
    const ushort* oT = xn;
    #pragma unroll
    for (int k2 = 0; k2 < 6; k2++) {
      const int e = t + k2*512;
      const int oc = e >> 5, q5 = e & 31;
      const int ty = q5 >> 2, tq = q5 & 3;
      const int m = (tq >> 1)*64 + ty*8 + (tq & 1)*4;
      const short4v ov = *(const short4v*)((const char*)oT + oc*264 + m*2);
      const size_t gidx = (size_t)(b*CC+oc)*65536 + (size_t)(y0+ty)*256 + x0 + tq*4;
      float4 res;
      res.x = bf2f((ushort)ov[0]);
      res.y = bf2f((ushort)ov[1]);
      res.z = bf2f((ushort)ov[2]);
      res.w = bf2f((ushort)ov[3]);
      *(float4*)(out + gidx) = res;
    }
  }
}

// ---------------- Kernel 2: RMSNorm + conv1x1 + GLU via MFMA -> y bf16 [b][hw][96] ----------------
__global__ __launch_bounds__(256, 2) void mlp1_kernel(
    const float* __restrict__ x1f,
    const ushort* __restrict__ x1b,
    const __hip_bfloat16* __restrict__ w1p,   // [ks][12][64][8] (mlp_norm_w folded)
    const float* __restrict__ w1_b,
    __hip_bfloat16* __restrict__ y)           // [b][hw][96]
{
  __shared__ ushort xn[128*104];
  const int blk = blockIdx.x;
  const int b   = blk >> 9;
  const int wpl = blk & 511;
  const int wy  = wpl >> 4, wxp = wpl & 15;
  const int t   = threadIdx.x;
  const int l   = t & 63;
  const int w   = __builtin_amdgcn_readfirstlane(t >> 6);
  const int lr  = l & 15, g = l >> 4;

  {
    const int p = t >> 1, half = t & 1;
    float xv[48];
    float ss = 0.f;
    if (x1b) {
      const ushort* xp = x1b + ((size_t)(b*96 + half*48)*512 + wpl)*128 + p;
      #pragma unroll
      for (int i = 0; i < 48; i++) { xv[i] = bf2f(xp[(size_t)i*65536]); ss += xv[i]*xv[i]; }
    } else {
      const int gy = wy*8 + ((p & 63) >> 3);
      const int gx = wxp*16 + (p >> 6)*8 + (p & 7);
      const float* xp = x1f + (size_t)(b*CC + half*48)*65536 + (size_t)gy*256 + gx;
      #pragma unroll
      for (int i = 0; i < 48; i++) { xv[i] = xp[(size_t)i*65536]; ss += xv[i]*xv[i]; }
    }
    ss += __shfl_xor(ss, 1);
    const float s = rsqrtf(ss*(1.f/96.f) + 1e-6f);
    #pragma unroll
    for (int i = 0; i < 48; i += 2) {
      const int c = half*48 + i;
      union { ushort u[2]; uint v; } pk;
      pk.u[0] = f2bf(xv[i]   * s);     // mlp_norm_w folded into w1p
      pk.u[1] = f2bf(xv[i+1] * s);
      *(uint*)(&xn[p*104 + c]) = pk.v;
    }
  }
  // wave-private rows -> no barrier needed before GEMM

  f32x4 acc[2][12];
  #pragma unroll
  for (int m2 = 0; m2 < 2; m2++)
    #pragma unroll
    for (int nt = 0; nt < 12; nt++) acc[m2][nt] = (f32x4)0.f;

  #pragma unroll
  for (int ks = 0; ks < 3; ks++) {
    short8 afr[2];
    #pragma unroll
    for (int m2 = 0; m2 < 2; m2++)
      afr[m2] = *(const short8*)((const char*)xn + (lr + (w*2+m2)*16)*208 + g*16 + ks*64);
    #pragma unroll
    for (int nt = 0; nt < 12; nt++) {
      const short8 bfr = *(const short8*)(w1p + ((ks*12+nt)*64 + l)*8);
      #pragma unroll
      for (int m2 = 0; m2 < 2; m2++)
        acc[m2][nt] = __builtin_amdgcn_mfma_f32_16x16x32_bf16(afr[m2], bfr, acc[m2][nt], 0, 0, 0);
    }
  }

  #pragma unroll
  for (int m2 = 0; m2 < 2; m2++)
    #pragma unroll
    for (int nt = 0; nt < 6; nt++) {
      const int oc = nt*16 + lr;
      const float ab = w1_b[oc], gb = w1_b[96+oc];
      #pragma unroll
      for (int r = 0; r < 4; r++) {
        const int row = (w*2+m2)*16 + g*4 + r;
        const float a  = acc[m2][nt][r]   + ab;
        const float gg = acc[m2][nt+6][r] + gb;
        xn[row*104 + oc] = f2bf(a / (1.f + __expf(-gg)));
      }
    }
  __syncthreads();

  // ---- y stores: map local px -> global pixel ----
  #pragma unroll
  for (int k2 = 0; k2 < 6; k2++) {
    const int e = t + k2*256;
    const int p = e / 12, ch = e - p*12;
    const int gy = wy*8 + ((p & 63) >> 3);
    const int gx = wxp*16 + (p >> 6)*8 + (p & 7);
    const short8 v = *(const short8*)(&xn[p*104 + ch*8]);
    *(short8*)((ushort*)y + ((size_t)(b*65536 + gy*256 + gx))*96 + ch*8) = v;
  }
}

// ---------------- Kernel 3: conv3x3 — MFMA implicit GEMM with LDS-staged B ----------------
__global__ __launch_bounds__(256, 2) void conv3_kernel(
    const __hip_bfloat16* __restrict__ y,    // [b][hw][96]
    const __hip_bfloat16* __restrict__ w2p,
    const float* __restrict__ w2_b,
    const ushort* __restrict__ x1b,          // bf16 residual (or null)
    float* __restrict__ xout)                // final f32 output
{
  extern __shared__ char smem[];
  ushort* A  = (ushort*)smem;                 // [264 segs][104 pad] bf16
  ushort* Bs = (ushort*)(smem + 54912);       // [3 kc][6 nf][64 lane][8] bf16 (one tap)

  const int vbid = (blockIdx.x & 7)*256 + (blockIdx.x >> 3);
  const int b   = vbid >> 9;
  const int rem = vbid & 511;
  const int ch  = rem >> 7;          // px chunk 0..3
  const int rp  = rem & 127;         // row pair
  const int px0 = ch << 6;
  const int t   = threadIdx.x;
  const int w   = __builtin_amdgcn_readfirstlane(t >> 6);
  const int l   = t & 63;
  const int m15 = l & 15, lh = l >> 4;

  // ---- stage A (104-pad, proven layout) ----
  for (int e = t; e < 3168; e += 256) {
    const int seg  = e / 12;
    const int part = e - seg*12;
    const int ky = seg / 66;
    const int px = seg - ky*66;
    const int gy = min(255, max(0, 2*rp + ky - 1));
    const int gx = min(255, max(0, px0 + px - 1));
    const short8 v = *(const short8*)(y + ((size_t)(b*65536 + gy*256 + gx))*96 + part*8);
    *(short8*)(A + seg*104 + part*8) = v;
  }

  // ---- prefetch residual into registers ----
  f32x4 resid[2][6];
  const int gpx = px0 + 16*w + lh*4;
  if (x1b) {
    #pragma unroll
    for (int rw = 0; rw < 2; rw++) {
      const int gyo = 2*rp + rw;
      const int wpl = (gyo >> 3)*16 + (gpx >> 4);
      const int gx4 = gpx & 15;
      const int m = (gx4 >> 3)*64 + (gyo & 7)*8 + (gx4 & 7);
      #pragma unroll
      for (int nf = 0; nf < 6; nf++) {
        const int oc = nf*16 + m15;
        const short4v rv = *(const short4v*)(x1b + ((size_t)(b*96+oc)*512 + wpl)*128 + m);
        #pragma unroll
        for (int q = 0; q < 4; q++) resid[rw][nf][q] = bf2f((ushort)rv[q]);
      }
    }
  } else {
    #pragma unroll
    for (int rw = 0; rw < 2; rw++)
      #pragma unroll
      for (int nf = 0; nf < 6; nf++) {
        const int oc = nf*16 + m15;
        resid[rw][nf] = *(const f32x4*)(xout + ((size_t)(b*CC + oc))*65536 + (size_t)(2*rp+rw)*256 + gpx);
      }
  }

  // ---- preload tap 0 B-frags into regs ----
  uint2 breg[9];
  {
    const uint2* src = (const uint2*)w2p;
    #pragma unroll
    for (int i = 0; i < 9; i++) breg[i] = src[t + i*256];
  }

  f32x4 acc0[6], acc1[6];
  #pragma unroll
  for (int nf = 0; nf < 6; ++nf) { acc0[nf] = (f32x4)0.f; acc1[nf] = (f32x4)0.f; }

  for (int tap = 0; tap < 9; ++tap) {
    __syncthreads();   // (a) prior tap's Bs reads done
    {
      uint2* dst = (uint2*)Bs;
      #pragma unroll
      for (int i = 0; i < 9; i++) dst[t + i*256] = breg[i];
    }
    if (tap < 8) {
      const uint2* src = (const uint2*)w2p + (tap+1)*2304;
      #pragma unroll
      for (int i = 0; i < 9; i++) breg[i] = src[t + i*256];
    }
    __syncthreads();   // (b) Bs ready (tap 0: A also ready)

    const int ky = tap / 3, kx = tap - ky*3;
    #pragma unroll
    for (int kc = 0; kc < 3; ++kc) {
      const int cb = kc*32 + lh*8;
      const short8 a0 = *(const short8*)(A + ((ky  )*66 + 16*w + m15 + kx)*104 + cb);
      const short8 a1 = *(const short8*)(A + ((ky+1)*66 + 16*w + m15 + kx)*104 + cb);
      #pragma unroll
      for (int nf = 0; nf < 6; ++nf) {
        const short8 bf = *(const short8*)(Bs + ((kc*6+nf)*64 + l)*8);
        acc0[nf] = __builtin_amdgcn_mfma_f32_16x16x32_bf16(a0, bf, acc0[nf], 0, 0, 0);
        acc1[nf] = __builtin_amdgcn_mfma_f32_16x16x32_bf16(a1, bf, acc1[nf], 0, 0, 0);
      }
    }
  }

  // ---- direct-to-global epilogue: bias + leaky + residual ----
  #pragma unroll
  for (int nf = 0; nf < 6; ++nf) {
    const int oc = nf*16 + m15;
    const float bb = w2_b[oc];
    #pragma unroll
    for (int rw = 0; rw < 2; rw++) {
      const f32x4 av = rw ? acc1[nf] : acc0[nf];
      float* op = xout + ((size_t)(b*CC + oc))*65536 + (size_t)(2*rp+rw)*256 + gpx;
      f32x4 r = resid[rw][nf];
      #pragma unroll
      for (int q = 0; q < 4; ++q) {
        float u = av[q] + bb;
        u = (u >= 0.f) ? u : 0.1f*u;
        r[q] += u;
      }
      *(f32x4*)op = r;
    }
  }
}

extern "C" void kernel_launch(void* const* d_in, const int* in_sizes, int n_in,
                              void* d_out, int out_size, void* d_ws, size_t ws_size,
                              hipStream_t stream)
{
  (void)in_sizes; (void)n_in; (void)out_size;
  const float* x      = (const float*)d_in[0];
  const float* norm_w = (const float*)d_in[1];
  const float* qkv_w  = (const float*)d_in[2];
  const float* qkv_b  = (const float*)d_in[3];
  const float* proj_w = (const float*)d_in[4];
  const float* proj_b = (const float*)d_in[5];
  const float* btab   = (const float*)d_in[6];
  const float* mlpnw  = (const float*)d_in[7];
  const float* w1w    = (const float*)d_in[8];
  const float* w1b    = (const float*)d_in[9];
  const float* w2w    = (const float*)d_in[10];
  const float* w2b    = (const float*)d_in[11];
  float* out = (float*)d_out;

  char* ws = (char*)d_ws;
  __hip_bfloat16* y     = (__hip_bfloat16*)ws;                    // 50,331,648 B
  __hip_bfloat16* w2p   = (__hip_bfloat16*)(ws + 50331648);       // 165,888 B
  __hip_bfloat16* qkvp  = (__hip_bfloat16*)(ws + 50497536);       // 73,728 B
  float*          qkvb2 = (float*)(ws + 50571264);                // 1,536 B
  __hip_bfloat16* projp = (__hip_bfloat16*)(ws + 50572800);       // 18,432 B
  __hip_bfloat16* w1p   = (__hip_bfloat16*)(ws + 50591232);       // 36,864 B
  __hip_bfloat16* vwp   = (__hip_bfloat16*)(ws + 50628096);       // 24,576 B
  // bf16 x1 intermediate (wp-tiled), only if workspace allows
  const size_t X1B_OFF = 50652672;
  const size_t X1B_END = X1B_OFF + (size_t)4*96*512*128*2;        // 100,984,320
  ushort* x1b = (ws_size >= X1B_END) ? (ushort*)(ws + X1B_OFF) : nullptr;

  prep_kernel<<<626, 256, 0, stream>>>(qkv_w, qkv_b, proj_w, w2w, w1w, norm_w, mlpnw,
                                       qkvp, qkvb2, projp, w2p, w1p, vwp);

  attn_kernel<<<2048, 512, 52100, stream>>>(x, qkvp, qkvb2, vwp, projp, proj_b, btab,
                                            out, x1b);
  mlp1_kernel<<<2048, 256, 0, stream>>>(out, x1b, w1p, w1b, y);
  conv3_kernel<<<2048, 256, 73344, stream>>>(y, w2p, w2b, x1b, out);
}